// Round 4
// baseline (273.325 us; speedup 1.0000x reference)
//
#include <hip/hip_runtime.h>
#include <math.h>

// x [B=256, T=4096, C=32] f32 -> out [B, 64, 64, 32] f32, PAA=64, GADF.
// SPLIT-KERNEL design (R4): R1-R3 all pinned at ~81us / 2.47 TB/s despite
// occupancy 9->40% and contiguous streaming; the invariant was the monolithic
// read-phase/barrier/write-phase block. Here:
//   Kernel A: pure read-stream reduction -> raw segment sums + partial
//             min/max in workspace (PAA mean commutes with rescale).
//   Kernel B: pure write-stream expansion (fillBuffer-shaped: 8 blocks/CU),
//             recomputes p,y per block from the tiny ws tables (L2-hot).
#define BB   256
#define TT   4096
#define CC   32
#define PP   64
#define PSTR 33

__device__ __forceinline__ float4 f4min(float4 a, float4 b) {
    return make_float4(fminf(a.x,b.x), fminf(a.y,b.y), fminf(a.z,b.z), fminf(a.w,b.w));
}
__device__ __forceinline__ float4 f4max(float4 a, float4 b) {
    return make_float4(fmaxf(a.x,b.x), fmaxf(a.y,b.y), fmaxf(a.z,b.z), fmaxf(a.w,b.w));
}
__device__ __forceinline__ void f4add(float4& a, float4 v) {
    a.x += v.x; a.y += v.y; a.z += v.z; a.w += v.w;
}
__device__ __forceinline__ float4 shflxor4(float4 v, int m) {
    return make_float4(__shfl_xor(v.x, m), __shfl_xor(v.y, m),
                       __shfl_xor(v.z, m), __shfl_xor(v.w, m));
}

// ---- Kernel A: 1024 blocks x 256 threads. Block = (batch b, quarter chunk).
// Reads 128 KB contiguous; writes 16 raw segment sums + partial min/max.
__global__ __launch_bounds__(256) void gaf_reduce(const float* __restrict__ x,
                                                  float* __restrict__ segsum,
                                                  float* __restrict__ pmin,
                                                  float* __restrict__ pmax) {
    __shared__ float redmin[4 * CC], redmax[4 * CC];
    const int tid  = threadIdx.x;
    const int cg   = tid & 7;       // channels [4cg, 4cg+4)
    const int r    = tid >> 3;      // 0..31: t in [chunk*1024 + 32r, +32)
    const int wave = tid >> 6;
    const int lane = tid & 63;
    const int b     = blockIdx.x >> 2;
    const int chunk = blockIdx.x & 3;

    const float4* xp = (const float4*)x + (size_t)b * 32768 + chunk * 8192 + r * 256 + cg;

    const float FBIG = 3.402823466e+38f;
    float4 mn  = make_float4(FBIG, FBIG, FBIG, FBIG);
    float4 mx  = make_float4(-FBIG, -FBIG, -FBIG, -FBIG);
    float4 acc = make_float4(0.f, 0.f, 0.f, 0.f);

    #pragma unroll
    for (int g = 0; g < 4; ++g) {
        float4 buf[8];
        #pragma unroll
        for (int u = 0; u < 8; ++u) buf[u] = xp[(g * 8 + u) * 8];
        #pragma unroll
        for (int u = 0; u < 8; ++u) {
            mn = f4min(mn, buf[u]); mx = f4max(mx, buf[u]); f4add(acc, buf[u]);
        }
    }

    // full segment sum: r even/odd pair covers one 64-step segment (lane^8)
    float4 seg = acc;
    f4add(seg, shflxor4(acc, 8));

    // min/max across the 8 r-values in this wave (lane bits 3..5)
    #pragma unroll
    for (int m = 8; m <= 32; m <<= 1) {
        mn = f4min(mn, shflxor4(mn, m));
        mx = f4max(mx, shflxor4(mx, m));
    }
    if (lane < 8) {
        *(float4*)&redmin[wave * CC + cg * 4] = mn;
        *(float4*)&redmax[wave * CC + cg * 4] = mx;
    }

    // write raw segment sums (r-even lanes hold s = chunk*16 + r/2)
    if ((r & 1) == 0) {
        const int s = chunk * 16 + (r >> 1);
        *(float4*)&segsum[((size_t)b * PP + s) * CC + cg * 4] = seg;
    }

    __syncthreads();
    if (tid < 8) {                  // tid == cg
        float4 m0 = *(const float4*)&redmin[0 * CC + tid * 4];
        float4 x0 = *(const float4*)&redmax[0 * CC + tid * 4];
        #pragma unroll
        for (int w = 1; w < 4; ++w) {
            m0 = f4min(m0, *(const float4*)&redmin[w * CC + tid * 4]);
            x0 = f4max(x0, *(const float4*)&redmax[w * CC + tid * 4]);
        }
        *(float4*)&pmin[((size_t)b * 4 + chunk) * CC + tid * 4] = m0;
        *(float4*)&pmax[((size_t)b * 4 + chunk) * CC + tid * 4] = x0;
    }
}

// ---- Kernel B: 2048 blocks x 256 threads. Block = (batch b, i-octet ib).
// Reads ~8.5 KB of ws (L2-hot), writes a contiguous 64 KB slab of out.
__global__ __launch_bounds__(256) void gaf_expand(const float* __restrict__ segsum,
                                                  const float* __restrict__ pmin,
                                                  const float* __restrict__ pmax,
                                                  float* __restrict__ out) {
    __shared__ float sp[PP * PSTR];
    __shared__ float sy[PP * PSTR];
    __shared__ float lmn[CC], linv[CC];

    const int tid = threadIdx.x;
    const int b   = blockIdx.x >> 3;
    const int ib  = blockIdx.x & 7;     // i in [8*ib, 8*ib+8)

    if (tid < 8) {                      // tid == cg
        float4 mn = *(const float4*)&pmin[((size_t)b * 4 + 0) * CC + tid * 4];
        float4 mx = *(const float4*)&pmax[((size_t)b * 4 + 0) * CC + tid * 4];
        #pragma unroll
        for (int c = 1; c < 4; ++c) {
            mn = f4min(mn, *(const float4*)&pmin[((size_t)b * 4 + c) * CC + tid * 4]);
            mx = f4max(mx, *(const float4*)&pmax[((size_t)b * 4 + c) * CC + tid * 4]);
        }
        float4 inv;
        inv.x = 1.0f / (mx.x - mn.x);  inv.y = 1.0f / (mx.y - mn.y);
        inv.z = 1.0f / (mx.z - mn.z);  inv.w = 1.0f / (mx.w - mn.w);
        *(float4*)&lmn[tid * 4]  = mn;
        *(float4*)&linv[tid * 4] = inv;
    }
    __syncthreads();

    // compute p,y into LDS: 512 (s,cg) items, 2 per thread
    const float s64 = 1.0f / 64.0f;
    #pragma unroll
    for (int it = 0; it < 2; ++it) {
        const int item = it * 256 + tid;
        const int s  = item >> 3;
        const int c  = item & 7;
        float4 raw = *(const float4*)&segsum[((size_t)b * PP + s) * CC + c * 4];
        float4 mn  = *(const float4*)&lmn[c * 4];
        float4 inv = *(const float4*)&linv[c * 4];
        float4 p, y;
        p.x = (raw.x * s64 - mn.x) * inv.x;  p.y = (raw.y * s64 - mn.y) * inv.y;
        p.z = (raw.z * s64 - mn.z) * inv.z;  p.w = (raw.w * s64 - mn.w) * inv.w;
        y.x = sqrtf(fmaxf(1.f - p.x * p.x, 0.f));  y.y = sqrtf(fmaxf(1.f - p.y * p.y, 0.f));
        y.z = sqrtf(fmaxf(1.f - p.z * p.z, 0.f));  y.w = sqrtf(fmaxf(1.f - p.w * p.w, 0.f));
        *(float4*)&sp[s * PSTR + c * 4] = p;
        *(float4*)&sy[s * PSTR + c * 4] = y;
    }
    __syncthreads();

    // out[b,i,j,c] = y_i*p_j - p_i*y_j ; thread owns (j0, j0+32) x cg, 8 i's
    const int cg = tid & 7;
    const int j0 = tid >> 3;            // 0..31
    const float4 pj0 = *(const float4*)&sp[j0 * PSTR + cg * 4];
    const float4 yj0 = *(const float4*)&sy[j0 * PSTR + cg * 4];
    const float4 pj1 = *(const float4*)&sp[(j0 + 32) * PSTR + cg * 4];
    const float4 yj1 = *(const float4*)&sy[(j0 + 32) * PSTR + cg * 4];

    float4* ob = (float4*)out + (size_t)b * 32768;

    #pragma unroll
    for (int ii = 0; ii < 8; ++ii) {
        const int i = ib * 8 + ii;
        const float4 pi = *(const float4*)&sp[i * PSTR + cg * 4];
        const float4 yi = *(const float4*)&sy[i * PSTR + cg * 4];
        float4 r0, r1;
        r0.x = yi.x * pj0.x - pi.x * yj0.x;  r0.y = yi.y * pj0.y - pi.y * yj0.y;
        r0.z = yi.z * pj0.z - pi.z * yj0.z;  r0.w = yi.w * pj0.w - pi.w * yj0.w;
        r1.x = yi.x * pj1.x - pi.x * yj1.x;  r1.y = yi.y * pj1.y - pi.y * yj1.y;
        r1.z = yi.z * pj1.z - pi.z * yj1.z;  r1.w = yi.w * pj1.w - pi.w * yj1.w;
        ob[i * 512 + j0 * 8 + cg]       = r0;
        ob[i * 512 + 256 + j0 * 8 + cg] = r1;
    }
}

extern "C" void kernel_launch(void* const* d_in, const int* in_sizes, int n_in,
                              void* d_out, int out_size, void* d_ws, size_t ws_size,
                              hipStream_t stream) {
    const float* x = (const float*)d_in[0];
    float* out = (float*)d_out;
    float* segsum = (float*)d_ws;                    // [256][64][32] = 2 MB
    float* pmin   = segsum + (size_t)BB * PP * CC;   // [256][4][32]
    float* pmax   = pmin + (size_t)BB * 4 * CC;      // [256][4][32]

    gaf_reduce<<<BB * 4, 256, 0, stream>>>(x, segsum, pmin, pmax);
    gaf_expand<<<BB * 8, 256, 0, stream>>>(segsum, pmin, pmax, out);
}